// Round 11
// baseline (975.916 us; speedup 1.0000x reference)
//
#include <hip/hip_runtime.h>
#include <cstdint>

#define G_     64
#define NPG_   400
#define DEG_   40
#define NN     (G_*NPG_)        // 25600
#define EE     (G_*NPG_*DEG_)   // 1024000
#define EMB_   16
#define HID_   192
#define OC_    128
#define MODEL_ 64
#define ODIM_  2
#define DEMO_  5
#define KP_    416              // adjacency K padded to 13*32

typedef __attribute__((ext_vector_type(8))) short short8;
typedef __attribute__((ext_vector_type(4))) float f32x4;

// ---- packed split-bf16: uint = (bf16(v) << 16) | bf16(v - bf16(v)) ----
__device__ __forceinline__ float urecon(unsigned u) {
  return __uint_as_float(u & 0xFFFF0000u) + __uint_as_float(u << 16);
}
__device__ __forceinline__ unsigned upack(float v) {
  unsigned u = __float_as_uint(v);
  unsigned hb = u & 0xFFFF0000u;
  float r = v - __uint_as_float(hb);           // exact
  return hb | (__float_as_uint(r) >> 16);
}

// ---------------- degree (by src) ----------------
__global__ void k_deg(const int* __restrict__ src, const float* __restrict__ ea,
                      float* __restrict__ deg) {
  int e = blockIdx.x * 256 + threadIdx.x;
  if (e < EE) atomicAdd(&deg[src[e]], ea[e]);
}

// ---------------- dense adjacency accumulate: Af[g][dst_l][src_l] += norm ----------------
__global__ void k_fillA(const int* __restrict__ src, const int* __restrict__ dst,
                        const float* __restrict__ ea, const float* __restrict__ deg,
                        float* __restrict__ Af) {
  int e = blockIdx.x * 256 + threadIdx.x;
  if (e >= EE) return;
  int s = src[e], d = dst[e];
  float ds_ = deg[s], dd_ = deg[d];
  float a = ds_ > 0.f ? rsqrtf(ds_) : 0.f;
  float b = dd_ > 0.f ? rsqrtf(dd_) : 0.f;
  float nm = -a * ea[e] * b;
  int g = d / NPG_;                         // src same group by construction
  int dl = d - g * NPG_, sl = s - g * NPG_;
  atomicAdd(&Af[((size_t)g * NPG_ + dl) * KP_ + sl], nm);
}

// in-place pack fp32 -> split-bf16 packed uint (zeros stay zeros)
__global__ void k_packA(unsigned* __restrict__ A, int n) {
  int i = blockIdx.x * 256 + threadIdx.x;
  if (i < n) A[i] = upack(__uint_as_float(A[i]));
}

// ---------------- W pre-split: Wt_hi/lo[n][kp] ushort, transposed + zero-padded K ----------------
__global__ void k_wsplit(const float* __restrict__ W, unsigned short* __restrict__ wh,
                         unsigned short* __restrict__ wl, int don, int ktot, int kp) {
  int i = blockIdx.x * 256 + threadIdx.x;
  if (i >= don * kp) return;
  int n = i / kp, k = i - n * kp;
  float v = (k < ktot) ? W[(size_t)k * don + n] : 0.f;
  unsigned u = __float_as_uint(v);
  unsigned hb = u & 0xFFFF0000u;
  float r = v - __uint_as_float(hb);
  wh[i] = (unsigned short)(hb >> 16);
  wl[i] = (unsigned short)(__float_as_uint(r) >> 16);
}

// ---------------- embedding gather (packed output) ----------------
__global__ void k_embed(const int* __restrict__ ids, const float* __restrict__ emb,
                        unsigned* __restrict__ x) {
  int i = blockIdx.x * 256 + threadIdx.x;
  if (i >= NN * EMB_) return;
  int n = i >> 4, f = i & 15;
  x[i] = upack(emb[ids[n] * EMB_ + f]);
}

// ---------------- prop as dense MFMA GEMM: out[g] = A[g] (400x416) @ X[g] (400xDI) ----------------
// Split-bf16 3-term (AhBh + AhBl + AlBh), fp32 accum. Block = 64 rows x DI cols,
// 4 waves split along N (DI=192: 3 n-tiles each) or M (DI=16). A packed-uint rows
// staged linearly; X-tile staged TRANSPOSED [n][k] (stride 36 -> <=2-way banks).
// XCD swizzle: group g on XCD g&7. FUSE: out = 2*(A@X) - t0 (Chebyshev).
template<int DI, bool FUSE>
__global__ __launch_bounds__(256)
void k_propm(const unsigned* __restrict__ Ap, const unsigned* __restrict__ X,
             const unsigned* __restrict__ t0, unsigned* __restrict__ outp) {
  constexpr int KT = KP_ / 32;              // 13
  constexpr int MI_T = (DI >= 64) ? 4 : 1;  // m-frags per wave
  constexpr int NJ_T = (DI >= 64) ? (DI / 64) : 1;  // n-frags per wave
  __shared__ __align__(16) unsigned As[64][36];
  __shared__ __align__(16) unsigned Xs[DI][36];

  const int b = blockIdx.x;
  const int xcd = b & 7, kb_ = b >> 3;
  const int rt = kb_ % 7, gh = kb_ / 7;
  const int g = (gh << 3) | xcd;
  const int rowbase = rt * 64;              // local row base (may exceed 400 on tail)
  const int nbase = g * NPG_;
  const int tid = threadIdx.x;
  const int l = tid & 63, w = tid >> 6;
  const int lm = l & 15;
  const int kq = (l >> 4) * 8;
  const int m0 = (DI >= 64) ? 0 : w * 16;
  const int n0 = (DI >= 64) ? w * (NJ_T * 16) : 0;
  const unsigned* Ag = Ap + (size_t)g * NPG_ * KP_;

  f32x4 acc[MI_T][NJ_T];
#pragma unroll
  for (int mi = 0; mi < MI_T; ++mi)
#pragma unroll
    for (int jj = 0; jj < NJ_T; ++jj) acc[mi][jj] = (f32x4)0.f;

  for (int kt = 0; kt < KT; ++kt) {
    if (kt) __syncthreads();
    const int k0 = kt * 32;
    // stage A tile 64x32 (row guard; cols >=400 are zeros in Ap already)
#pragma unroll
    for (int it = 0; it < 8; ++it) {
      int i = tid + it * 256;
      int r = i >> 5, kk = i & 31;
      int gr = rowbase + r;
      As[r][kk] = (gr < NPG_) ? Ag[(size_t)gr * KP_ + k0 + kk] : 0u;
    }
    // stage X tile 32xDI transposed -> Xs[n][kk]; k guard (pad rows -> 0)
#pragma unroll
    for (int it = 0; it < (32 * DI) / 256; ++it) {
      int i = tid + it * 256;
      int kk = i / DI, n = i - kk * DI;
      int ks = k0 + kk;
      Xs[n][kk] = (ks < NPG_) ? X[(size_t)(nbase + ks) * DI + n] : 0u;
    }
    __syncthreads();

    short8 ah[MI_T], al[MI_T];
#pragma unroll
    for (int mi = 0; mi < MI_T; ++mi) {
      unsigned ua[8];
      *(uint4*)&ua[0] = *(const uint4*)&As[m0 + mi * 16 + lm][kq];
      *(uint4*)&ua[4] = *(const uint4*)&As[m0 + mi * 16 + lm][kq + 4];
#pragma unroll
      for (int j2 = 0; j2 < 8; ++j2) {
        ah[mi][j2] = (short)(ua[j2] >> 16);
        al[mi][j2] = (short)(ua[j2] & 0xFFFFu);
      }
    }
    short8 bh[NJ_T], bl[NJ_T];
#pragma unroll
    for (int jj = 0; jj < NJ_T; ++jj) {
      unsigned ub[8];
      int n = n0 + jj * 16 + lm;
      *(uint4*)&ub[0] = *(const uint4*)&Xs[n][kq];
      *(uint4*)&ub[4] = *(const uint4*)&Xs[n][kq + 4];
#pragma unroll
      for (int j2 = 0; j2 < 8; ++j2) {
        bh[jj][j2] = (short)(ub[j2] >> 16);
        bl[jj][j2] = (short)(ub[j2] & 0xFFFFu);
      }
    }
    // term-major: interleaves independent accs between same-acc chained MFMAs
#pragma unroll
    for (int mi = 0; mi < MI_T; ++mi)
#pragma unroll
      for (int jj = 0; jj < NJ_T; ++jj)
        acc[mi][jj] = __builtin_amdgcn_mfma_f32_16x16x32_bf16(ah[mi], bh[jj], acc[mi][jj], 0, 0, 0);
#pragma unroll
    for (int mi = 0; mi < MI_T; ++mi)
#pragma unroll
      for (int jj = 0; jj < NJ_T; ++jj)
        acc[mi][jj] = __builtin_amdgcn_mfma_f32_16x16x32_bf16(ah[mi], bl[jj], acc[mi][jj], 0, 0, 0);
#pragma unroll
    for (int mi = 0; mi < MI_T; ++mi)
#pragma unroll
      for (int jj = 0; jj < NJ_T; ++jj)
        acc[mi][jj] = __builtin_amdgcn_mfma_f32_16x16x32_bf16(al[mi], bh[jj], acc[mi][jj], 0, 0, 0);
  }

  const int r0 = (l >> 4) * 4;
#pragma unroll
  for (int mi = 0; mi < MI_T; ++mi) {
#pragma unroll
    for (int jj = 0; jj < NJ_T; ++jj) {
      int col = n0 + jj * 16 + lm;
#pragma unroll
      for (int r = 0; r < 4; ++r) {
        int gr = rowbase + m0 + mi * 16 + r0 + r;
        if (gr < NPG_) {
          size_t oi = (size_t)(nbase + gr) * DI + col;
          float v = acc[mi][jj][r];
          if constexpr (FUSE) v = 2.f * v - urecon(t0[oi]);
          outp[oi] = upack(v);
        }
      }
    }
  }
}

// ---------------- fused dense via split-bf16 MFMA, pre-split operands (unchanged r6) ----------------
template<int DI, int DO, bool LAST>
__global__ __launch_bounds__(256)
void k_densem(const unsigned* __restrict__ t0, const unsigned* __restrict__ t1,
              const unsigned* __restrict__ t2,
              const unsigned short* __restrict__ wh, const unsigned short* __restrict__ wl,
              const float* __restrict__ bias, void* __restrict__ outv) {
  constexpr int KTOT = 3 * DI;
  constexpr int KT = (KTOT + 31) / 32;
  constexpr int KP = KT * 32;
  constexpr int NT = DO / 16;
  constexpr int XS = 36;
  constexpr int WS = 40;
  __shared__ __align__(16) unsigned Xu[64][XS];
  __shared__ __align__(16) unsigned short Whs[DO][WS];
  __shared__ __align__(16) unsigned short Wls[DO][WS];

  const int tid = threadIdx.x;
  const int rowbase = blockIdx.x * 64;
  const int l = tid & 63, w = tid >> 6;
  const int lm = l & 15;
  const int kb = (l >> 4) * 8;

  f32x4 acc[NT];
#pragma unroll
  for (int j = 0; j < NT; ++j) acc[j] = (f32x4)0.f;

  for (int kt = 0; kt < KT; ++kt) {
    if (kt) __syncthreads();
    const int k0 = kt * 32;
    if constexpr (DI % 32 == 0) {
      const int bb = k0 / DI, d0 = k0 - bb * DI;
      const unsigned* tb = bb == 0 ? t0 : (bb == 1 ? t1 : t2);
#pragma unroll
      for (int it = 0; it < 2; ++it) {
        int i = tid + it * 256;
        int r = i >> 3, q = i & 7;
        ((uint4*)&Xu[r][0])[q] = ((const uint4*)(tb + (size_t)(rowbase + r) * DI + d0))[q];
      }
    } else {
      for (int i = tid; i < 64 * 32; i += 256) {
        int r = i >> 5, kk = i & 31, kg = k0 + kk;
        unsigned u = 0;
        if (kg < KTOT) {
          int bb = kg / DI, d = kg - bb * DI;
          const unsigned* tb = bb == 0 ? t0 : (bb == 1 ? t1 : t2);
          u = tb[(size_t)(rowbase + r) * DI + d];
        }
        Xu[r][kk] = u;
      }
    }
    for (int i = tid; i < DO * 4; i += 256) {
      int n = i >> 2, q = i & 3;
      ((uint4*)&Whs[n][0])[q] = ((const uint4*)(wh + (size_t)n * KP + k0))[q];
    }
    for (int i = tid; i < DO * 4; i += 256) {
      int n = i >> 2, q = i & 3;
      ((uint4*)&Wls[n][0])[q] = ((const uint4*)(wl + (size_t)n * KP + k0))[q];
    }
    __syncthreads();

    unsigned ua[8];
    *(uint4*)&ua[0] = *(const uint4*)&Xu[w * 16 + lm][kb];
    *(uint4*)&ua[4] = *(const uint4*)&Xu[w * 16 + lm][kb + 4];
    short8 ah, al;
#pragma unroll
    for (int j2 = 0; j2 < 8; ++j2) {
      ah[j2] = (short)(ua[j2] >> 16);
      al[j2] = (short)(ua[j2] & 0xFFFFu);
    }
#pragma unroll
    for (int j = 0; j < NT; ++j) {
      int n = j * 16 + lm;
      short8 bh = *(const short8*)&Whs[n][kb];
      short8 bl = *(const short8*)&Wls[n][kb];
      acc[j] = __builtin_amdgcn_mfma_f32_16x16x32_bf16(ah, bh, acc[j], 0, 0, 0);
      acc[j] = __builtin_amdgcn_mfma_f32_16x16x32_bf16(ah, bl, acc[j], 0, 0, 0);
      acc[j] = __builtin_amdgcn_mfma_f32_16x16x32_bf16(al, bh, acc[j], 0, 0, 0);
    }
  }

  const int r0 = (l >> 4) * 4;
#pragma unroll
  for (int j = 0; j < NT; ++j) {
    int col = j * 16 + lm;
    float bv = bias[col];
#pragma unroll
    for (int r = 0; r < 4; ++r) {
      int row = rowbase + w * 16 + r0 + r;
      float val = acc[j][r] + bv;
      if (LAST) ((float*)outv)[(size_t)row * DO + col] = val;
      else      ((unsigned*)outv)[(size_t)row * DO + col] = upack(val);
    }
  }
}

// ---------------- mean pool per graph + concat demographics ----------------
__global__ void k_pool(const float* __restrict__ x, const float* __restrict__ demo,
                       float* __restrict__ feats) {
  int g = blockIdx.x, j = threadIdx.x;  // 128 threads
  const float* p = x + (size_t)g * NPG_ * OC_;
  float s = 0.f;
  for (int n = 0; n < NPG_; ++n) s += p[n * OC_ + j];
  feats[g * (OC_ + DEMO_) + j] = s * (1.f / NPG_);
  if (j < DEMO_) feats[g * (OC_ + DEMO_) + OC_ + j] = demo[g * DEMO_ + j];
}

// ---------------- classifier MLP ----------------
__global__ void k_cls(const float* __restrict__ feats,
                      const float* __restrict__ w1, const float* __restrict__ b1,
                      const float* __restrict__ w2, const float* __restrict__ b2,
                      float* __restrict__ out) {
  int g = blockIdx.x, j = threadIdx.x;  // 64 threads
  __shared__ float h[MODEL_];
  const float* f = feats + g * (OC_ + DEMO_);
  float a = b1[j];
  for (int i = 0; i < OC_ + DEMO_; ++i) a += f[i] * w1[i * MODEL_ + j];
  h[j] = fmaxf(a, 0.f);
  __syncthreads();
  if (j < ODIM_) {
    float o = b2[j];
    for (int i = 0; i < MODEL_; ++i) o += h[i] * w2[i * ODIM_ + j];
    out[g * ODIM_ + j] = o;
  }
}

extern "C" void kernel_launch(void* const* d_in, const int* in_sizes, int n_in,
                              void* d_out, int out_size, void* d_ws, size_t ws_size,
                              hipStream_t stream) {
  const int*   node_ids = (const int*)d_in[0];
  const int*   ei   = (const int*)d_in[1];
  const int*   src  = ei;
  const int*   dst  = ei + EE;
  const float* ea   = (const float*)d_in[3];
  const float* demo = (const float*)d_in[4];
  const float* emb  = (const float*)d_in[5];
  const float* w0   = (const float*)d_in[6];
  const float* b0   = (const float*)d_in[7];
  const float* w1   = (const float*)d_in[8];
  const float* b1   = (const float*)d_in[9];
  const float* w2   = (const float*)d_in[10];
  const float* b2   = (const float*)d_in[11];
  const float* cw1  = (const float*)d_in[12];
  const float* cb1  = (const float*)d_in[13];
  const float* cw2  = (const float*)d_in[14];
  const float* cb2  = (const float*)d_in[15];
  float* out = (float*)d_out;

  char* wp = (char*)d_ws;
  auto alloc = [&](size_t bytes) {
    char* p = wp;
    wp += (bytes + 255) & ~(size_t)255;
    return (void*)p;
  };
  constexpr size_t AELEMS = (size_t)G_ * NPG_ * KP_;   // 10,649,600
  float*          deg    = (float*)          alloc((size_t)NN * 4);
  float*          Af     = (float*)          alloc(AELEMS * 4);          // fp32 -> packed in place
  unsigned*       bufA   = (unsigned*)       alloc((size_t)NN * HID_ * 4);
  unsigned*       bufB   = (unsigned*)       alloc((size_t)NN * HID_ * 4);
  unsigned*       bufC   = (unsigned*)       alloc((size_t)NN * HID_ * 4);
  unsigned*       bufD   = (unsigned*)       alloc((size_t)NN * HID_ * 4);
  float*          feats  = (float*)          alloc((size_t)G_ * (OC_ + DEMO_) * 4);
  unsigned short* wh0    = (unsigned short*) alloc((size_t)192 * 64 * 2);
  unsigned short* wl0    = (unsigned short*) alloc((size_t)192 * 64 * 2);
  unsigned short* wh1    = (unsigned short*) alloc((size_t)192 * 576 * 2);
  unsigned short* wl1    = (unsigned short*) alloc((size_t)192 * 576 * 2);
  unsigned short* wh2    = (unsigned short*) alloc((size_t)128 * 576 * 2);
  unsigned short* wl2    = (unsigned short*) alloc((size_t)128 * 576 * 2);
  unsigned* Apk = (unsigned*)Af;

  hipMemsetAsync(deg, 0, (size_t)NN * 4, stream);
  hipMemsetAsync(Af, 0, AELEMS * 4, stream);

  k_deg   <<<(EE + 255) / 256, 256, 0, stream>>>(src, ea, deg);
  k_fillA <<<(EE + 255) / 256, 256, 0, stream>>>(src, dst, ea, deg, Af);
  k_packA <<<(int)((AELEMS + 255) / 256), 256, 0, stream>>>(Apk, (int)AELEMS);
  k_wsplit<<<(192 * 64  + 255) / 256, 256, 0, stream>>>(w0, wh0, wl0, 192, 48,  64);
  k_wsplit<<<(192 * 576 + 255) / 256, 256, 0, stream>>>(w1, wh1, wl1, 192, 576, 576);
  k_wsplit<<<(128 * 576 + 255) / 256, 256, 0, stream>>>(w2, wh2, wl2, 128, 576, 576);
  k_embed <<<(NN * EMB_ + 255) / 256, 256, 0, stream>>>(node_ids, emb, bufA);

  constexpr int PGRID = G_ * 7;   // 64 groups x 7 row-tiles (XCD-swizzled)

  // Layer 0: di=16, do=192.  Tx0=bufA, Tx1=bufB, Tx2=bufC -> bufD (packed)
  k_propm<16, false><<<PGRID, 256, 0, stream>>>(Apk, bufA, nullptr, bufB);
  k_propm<16, true ><<<PGRID, 256, 0, stream>>>(Apk, bufB, bufA, bufC);
  k_densem<16, 192, false><<<NN / 64, 256, 0, stream>>>(bufA, bufB, bufC, wh0, wl0, b0, bufD);

  // Layer 1: di=192, do=192.  Tx0=bufD -> bufC (packed)
  k_propm<192, false><<<PGRID, 256, 0, stream>>>(Apk, bufD, nullptr, bufA);
  k_propm<192, true ><<<PGRID, 256, 0, stream>>>(Apk, bufA, bufD, bufB);
  k_densem<192, 192, false><<<NN / 64, 256, 0, stream>>>(bufD, bufA, bufB, wh1, wl1, b1, bufC);

  // Layer 2: di=192, do=128.  Tx0=bufC -> bufD (fp32, feeds pool)
  k_propm<192, false><<<PGRID, 256, 0, stream>>>(Apk, bufC, nullptr, bufA);
  k_propm<192, true ><<<PGRID, 256, 0, stream>>>(Apk, bufA, bufC, bufB);
  k_densem<192, 128, true><<<NN / 64, 256, 0, stream>>>(bufC, bufA, bufB, wh2, wl2, b2, bufD);

  k_pool<<<G_, 128, 0, stream>>>((const float*)bufD, demo, feats);
  k_cls <<<G_, MODEL_, 0, stream>>>(feats, cw1, cb1, cw2, cb2, out);
}

// Round 12
// 643.983 us; speedup vs baseline: 1.5154x; 1.5154x over previous
//
#include <hip/hip_runtime.h>
#include <cstdint>

#define G_     64
#define NPG_   400
#define DEG_   40
#define NN     (G_*NPG_)        // 25600
#define EE     (G_*NPG_*DEG_)   // 1024000
#define EMB_   16
#define HID_   192
#define OC_    128
#define MODEL_ 64
#define ODIM_  2
#define DEMO_  5
#define KP_    416              // adjacency K padded to 13*32

typedef __attribute__((ext_vector_type(8))) short short8;
typedef __attribute__((ext_vector_type(4))) float f32x4;

// ---- packed split-bf16: uint = (bf16(v) << 16) | bf16(v - bf16(v)) ----
__device__ __forceinline__ float urecon(unsigned u) {
  return __uint_as_float(u & 0xFFFF0000u) + __uint_as_float(u << 16);
}
__device__ __forceinline__ unsigned upack(float v) {
  unsigned u = __float_as_uint(v);
  unsigned hb = u & 0xFFFF0000u;
  float r = v - __uint_as_float(hb);           // exact
  return hb | (__float_as_uint(r) >> 16);
}

// ---------------- degree (by src) ----------------
__global__ void k_deg(const int* __restrict__ src, const float* __restrict__ ea,
                      float* __restrict__ deg) {
  int e = blockIdx.x * 256 + threadIdx.x;
  if (e < EE) atomicAdd(&deg[src[e]], ea[e]);
}

// ---------------- dense adjacency accumulate: Af[g][dst_l][src_l] += norm ----------------
__global__ void k_fillA(const int* __restrict__ src, const int* __restrict__ dst,
                        const float* __restrict__ ea, const float* __restrict__ deg,
                        float* __restrict__ Af) {
  int e = blockIdx.x * 256 + threadIdx.x;
  if (e >= EE) return;
  int s = src[e], d = dst[e];
  float ds_ = deg[s], dd_ = deg[d];
  float a = ds_ > 0.f ? rsqrtf(ds_) : 0.f;
  float b = dd_ > 0.f ? rsqrtf(dd_) : 0.f;
  float nm = -a * ea[e] * b;
  int g = d / NPG_;                         // src same group by construction
  int dl = d - g * NPG_, sl = s - g * NPG_;
  atomicAdd(&Af[((size_t)g * NPG_ + dl) * KP_ + sl], nm);
}

// in-place pack fp32 -> split-bf16 packed uint (zeros stay zeros)
__global__ void k_packA(unsigned* __restrict__ A, int n) {
  int i = blockIdx.x * 256 + threadIdx.x;
  if (i < n) A[i] = upack(__uint_as_float(A[i]));
}

// ---------------- W pre-split: Wt_hi/lo[n][kp] ushort, transposed + zero-padded K ----------------
__global__ void k_wsplit(const float* __restrict__ W, unsigned short* __restrict__ wh,
                         unsigned short* __restrict__ wl, int don, int ktot, int kp) {
  int i = blockIdx.x * 256 + threadIdx.x;
  if (i >= don * kp) return;
  int n = i / kp, k = i - n * kp;
  float v = (k < ktot) ? W[(size_t)k * don + n] : 0.f;
  unsigned u = __float_as_uint(v);
  unsigned hb = u & 0xFFFF0000u;
  float r = v - __uint_as_float(hb);
  wh[i] = (unsigned short)(hb >> 16);
  wl[i] = (unsigned short)(__float_as_uint(r) >> 16);
}

// ---------------- embedding gather (packed output) ----------------
__global__ void k_embed(const int* __restrict__ ids, const float* __restrict__ emb,
                        unsigned* __restrict__ x) {
  int i = blockIdx.x * 256 + threadIdx.x;
  if (i >= NN * EMB_) return;
  int n = i >> 4, f = i & 15;
  x[i] = upack(emb[ids[n] * EMB_ + f]);
}

// ---------------- prop as dense MFMA GEMM: out[g] = A[g] (400x416) @ X[g] (400xDI) ----------------
// Round-12 re-tiling: block = 64 rows x NCH cols (NCH=64 for DI=192 -> grid x3 =
// 1344 blocks, 5.25/CU; LDS 18KB; per-kstep staging halved). 4 waves m-split
// (wave w: rows m0=w*16, all NCH cols, NJ=NCH/16 n-frags). Split-bf16 3-term.
// XCD swizzle: group g on XCD g&7. FUSE: out = 2*(A@X) - t0.
template<int DI, int NCH, bool FUSE>
__global__ __launch_bounds__(256)
void k_propm(const unsigned* __restrict__ Ap, const unsigned* __restrict__ X,
             const unsigned* __restrict__ t0, unsigned* __restrict__ outp) {
  constexpr int KT = KP_ / 32;              // 13
  constexpr int FC = DI / NCH;              // n-chunks per group
  constexpr int NJ = NCH / 16;              // n-frags per wave
  __shared__ __align__(16) unsigned As[64][36];
  __shared__ __align__(16) unsigned Xs[NCH][36];

  const int b = blockIdx.x;
  const int xcd = b & 7;
  const int idx = b >> 3;
  const int gh = idx / (7 * FC);
  const int rem = idx % (7 * FC);
  const int rt = rem / FC, nc = rem % FC;
  const int g = (gh << 3) | xcd;
  const int rowbase = rt * 64;              // local row base (tail tile guarded)
  const int c0 = nc * NCH;
  const int nbase = g * NPG_;
  const int tid = threadIdx.x;
  const int l = tid & 63, w = tid >> 6;
  const int lm = l & 15;
  const int kq = (l >> 4) * 8;
  const int m0 = w * 16;
  const unsigned* Ag = Ap + (size_t)g * NPG_ * KP_;

  f32x4 acc[NJ];
#pragma unroll
  for (int j = 0; j < NJ; ++j) acc[j] = (f32x4)0.f;

  for (int kt = 0; kt < KT; ++kt) {
    if (kt) __syncthreads();
    const int k0 = kt * 32;
    // stage A tile 64x32 via uint4 (2 per thread); rows >=400 zeroed
#pragma unroll
    for (int it = 0; it < 2; ++it) {
      int i = tid + it * 256;
      int r = i >> 3, q = i & 7;
      int gr = rowbase + r;
      uint4 v = make_uint4(0u, 0u, 0u, 0u);
      if (gr < NPG_) v = *(const uint4*)(Ag + (size_t)gr * KP_ + k0 + q * 4);
      *(uint4*)&As[r][q * 4] = v;
    }
    // stage X chunk 32xNCH transposed -> Xs[n][kk]; k guard (pad rows -> 0)
#pragma unroll
    for (int it = 0; it < (32 * NCH) / 256; ++it) {
      int i = tid + it * 256;
      int kk = i / NCH, n = i - kk * NCH;
      int ks = k0 + kk;
      Xs[n][kk] = (ks < NPG_) ? X[(size_t)(nbase + ks) * DI + c0 + n] : 0u;
    }
    __syncthreads();

    unsigned ua[8];
    *(uint4*)&ua[0] = *(const uint4*)&As[m0 + lm][kq];
    *(uint4*)&ua[4] = *(const uint4*)&As[m0 + lm][kq + 4];
    short8 ah, al;
#pragma unroll
    for (int j2 = 0; j2 < 8; ++j2) {
      ah[j2] = (short)(ua[j2] >> 16);
      al[j2] = (short)(ua[j2] & 0xFFFFu);
    }
    short8 bh[NJ], bl[NJ];
#pragma unroll
    for (int j = 0; j < NJ; ++j) {
      unsigned ub[8];
      *(uint4*)&ub[0] = *(const uint4*)&Xs[j * 16 + lm][kq];
      *(uint4*)&ub[4] = *(const uint4*)&Xs[j * 16 + lm][kq + 4];
#pragma unroll
      for (int j2 = 0; j2 < 8; ++j2) {
        bh[j][j2] = (short)(ub[j2] >> 16);
        bl[j][j2] = (short)(ub[j2] & 0xFFFFu);
      }
    }
#pragma unroll
    for (int j = 0; j < NJ; ++j)
      acc[j] = __builtin_amdgcn_mfma_f32_16x16x32_bf16(ah, bh[j], acc[j], 0, 0, 0);
#pragma unroll
    for (int j = 0; j < NJ; ++j)
      acc[j] = __builtin_amdgcn_mfma_f32_16x16x32_bf16(ah, bl[j], acc[j], 0, 0, 0);
#pragma unroll
    for (int j = 0; j < NJ; ++j)
      acc[j] = __builtin_amdgcn_mfma_f32_16x16x32_bf16(al, bh[j], acc[j], 0, 0, 0);
  }

  const int r0 = (l >> 4) * 4;
#pragma unroll
  for (int j = 0; j < NJ; ++j) {
    int col = c0 + j * 16 + lm;
#pragma unroll
    for (int r = 0; r < 4; ++r) {
      int gr = rowbase + m0 + r0 + r;
      if (gr < NPG_) {
        size_t oi = (size_t)(nbase + gr) * DI + col;
        float v = acc[j][r];
        if constexpr (FUSE) v = 2.f * v - urecon(t0[oi]);
        outp[oi] = upack(v);
      }
    }
  }
}

// ---------------- fused dense via split-bf16 MFMA, pre-split operands (unchanged) ----------------
template<int DI, int DO, bool LAST>
__global__ __launch_bounds__(256)
void k_densem(const unsigned* __restrict__ t0, const unsigned* __restrict__ t1,
              const unsigned* __restrict__ t2,
              const unsigned short* __restrict__ wh, const unsigned short* __restrict__ wl,
              const float* __restrict__ bias, void* __restrict__ outv) {
  constexpr int KTOT = 3 * DI;
  constexpr int KT = (KTOT + 31) / 32;
  constexpr int KP = KT * 32;
  constexpr int NT = DO / 16;
  constexpr int XS = 36;
  constexpr int WS = 40;
  __shared__ __align__(16) unsigned Xu[64][XS];
  __shared__ __align__(16) unsigned short Whs[DO][WS];
  __shared__ __align__(16) unsigned short Wls[DO][WS];

  const int tid = threadIdx.x;
  const int rowbase = blockIdx.x * 64;
  const int l = tid & 63, w = tid >> 6;
  const int lm = l & 15;
  const int kb = (l >> 4) * 8;

  f32x4 acc[NT];
#pragma unroll
  for (int j = 0; j < NT; ++j) acc[j] = (f32x4)0.f;

  for (int kt = 0; kt < KT; ++kt) {
    if (kt) __syncthreads();
    const int k0 = kt * 32;
    if constexpr (DI % 32 == 0) {
      const int bb = k0 / DI, d0 = k0 - bb * DI;
      const unsigned* tb = bb == 0 ? t0 : (bb == 1 ? t1 : t2);
#pragma unroll
      for (int it = 0; it < 2; ++it) {
        int i = tid + it * 256;
        int r = i >> 3, q = i & 7;
        ((uint4*)&Xu[r][0])[q] = ((const uint4*)(tb + (size_t)(rowbase + r) * DI + d0))[q];
      }
    } else {
      for (int i = tid; i < 64 * 32; i += 256) {
        int r = i >> 5, kk = i & 31, kg = k0 + kk;
        unsigned u = 0;
        if (kg < KTOT) {
          int bb = kg / DI, d = kg - bb * DI;
          const unsigned* tb = bb == 0 ? t0 : (bb == 1 ? t1 : t2);
          u = tb[(size_t)(rowbase + r) * DI + d];
        }
        Xu[r][kk] = u;
      }
    }
    for (int i = tid; i < DO * 4; i += 256) {
      int n = i >> 2, q = i & 3;
      ((uint4*)&Whs[n][0])[q] = ((const uint4*)(wh + (size_t)n * KP + k0))[q];
    }
    for (int i = tid; i < DO * 4; i += 256) {
      int n = i >> 2, q = i & 3;
      ((uint4*)&Wls[n][0])[q] = ((const uint4*)(wl + (size_t)n * KP + k0))[q];
    }
    __syncthreads();

    unsigned ua[8];
    *(uint4*)&ua[0] = *(const uint4*)&Xu[w * 16 + lm][kb];
    *(uint4*)&ua[4] = *(const uint4*)&Xu[w * 16 + lm][kb + 4];
    short8 ah, al;
#pragma unroll
    for (int j2 = 0; j2 < 8; ++j2) {
      ah[j2] = (short)(ua[j2] >> 16);
      al[j2] = (short)(ua[j2] & 0xFFFFu);
    }
#pragma unroll
    for (int j = 0; j < NT; ++j) {
      int n = j * 16 + lm;
      short8 bh = *(const short8*)&Whs[n][kb];
      short8 bl = *(const short8*)&Wls[n][kb];
      acc[j] = __builtin_amdgcn_mfma_f32_16x16x32_bf16(ah, bh, acc[j], 0, 0, 0);
      acc[j] = __builtin_amdgcn_mfma_f32_16x16x32_bf16(ah, bl, acc[j], 0, 0, 0);
      acc[j] = __builtin_amdgcn_mfma_f32_16x16x32_bf16(al, bh, acc[j], 0, 0, 0);
    }
  }

  const int r0 = (l >> 4) * 4;
#pragma unroll
  for (int j = 0; j < NT; ++j) {
    int col = j * 16 + lm;
    float bv = bias[col];
#pragma unroll
    for (int r = 0; r < 4; ++r) {
      int row = rowbase + w * 16 + r0 + r;
      float val = acc[j][r] + bv;
      if (LAST) ((float*)outv)[(size_t)row * DO + col] = val;
      else      ((unsigned*)outv)[(size_t)row * DO + col] = upack(val);
    }
  }
}

// ---------------- mean pool per graph + concat demographics ----------------
__global__ void k_pool(const float* __restrict__ x, const float* __restrict__ demo,
                       float* __restrict__ feats) {
  int g = blockIdx.x, j = threadIdx.x;  // 128 threads
  const float* p = x + (size_t)g * NPG_ * OC_;
  float s = 0.f;
  for (int n = 0; n < NPG_; ++n) s += p[n * OC_ + j];
  feats[g * (OC_ + DEMO_) + j] = s * (1.f / NPG_);
  if (j < DEMO_) feats[g * (OC_ + DEMO_) + OC_ + j] = demo[g * DEMO_ + j];
}

// ---------------- classifier MLP ----------------
__global__ void k_cls(const float* __restrict__ feats,
                      const float* __restrict__ w1, const float* __restrict__ b1,
                      const float* __restrict__ w2, const float* __restrict__ b2,
                      float* __restrict__ out) {
  int g = blockIdx.x, j = threadIdx.x;  // 64 threads
  __shared__ float h[MODEL_];
  const float* f = feats + g * (OC_ + DEMO_);
  float a = b1[j];
  for (int i = 0; i < OC_ + DEMO_; ++i) a += f[i] * w1[i * MODEL_ + j];
  h[j] = fmaxf(a, 0.f);
  __syncthreads();
  if (j < ODIM_) {
    float o = b2[j];
    for (int i = 0; i < MODEL_; ++i) o += h[i] * w2[i * ODIM_ + j];
    out[g * ODIM_ + j] = o;
  }
}

extern "C" void kernel_launch(void* const* d_in, const int* in_sizes, int n_in,
                              void* d_out, int out_size, void* d_ws, size_t ws_size,
                              hipStream_t stream) {
  const int*   node_ids = (const int*)d_in[0];
  const int*   ei   = (const int*)d_in[1];
  const int*   src  = ei;
  const int*   dst  = ei + EE;
  const float* ea   = (const float*)d_in[3];
  const float* demo = (const float*)d_in[4];
  const float* emb  = (const float*)d_in[5];
  const float* w0   = (const float*)d_in[6];
  const float* b0   = (const float*)d_in[7];
  const float* w1   = (const float*)d_in[8];
  const float* b1   = (const float*)d_in[9];
  const float* w2   = (const float*)d_in[10];
  const float* b2   = (const float*)d_in[11];
  const float* cw1  = (const float*)d_in[12];
  const float* cb1  = (const float*)d_in[13];
  const float* cw2  = (const float*)d_in[14];
  const float* cb2  = (const float*)d_in[15];
  float* out = (float*)d_out;

  char* wp = (char*)d_ws;
  auto alloc = [&](size_t bytes) {
    char* p = wp;
    wp += (bytes + 255) & ~(size_t)255;
    return (void*)p;
  };
  constexpr size_t AELEMS = (size_t)G_ * NPG_ * KP_;   // 10,649,600
  float*          deg    = (float*)          alloc((size_t)NN * 4);
  float*          Af     = (float*)          alloc(AELEMS * 4 + 256); // +tail pad
  unsigned*       bufA   = (unsigned*)       alloc((size_t)NN * HID_ * 4);
  unsigned*       bufB   = (unsigned*)       alloc((size_t)NN * HID_ * 4);
  unsigned*       bufC   = (unsigned*)       alloc((size_t)NN * HID_ * 4);
  unsigned*       bufD   = (unsigned*)       alloc((size_t)NN * HID_ * 4);
  float*          feats  = (float*)          alloc((size_t)G_ * (OC_ + DEMO_) * 4);
  unsigned short* wh0    = (unsigned short*) alloc((size_t)192 * 64 * 2);
  unsigned short* wl0    = (unsigned short*) alloc((size_t)192 * 64 * 2);
  unsigned short* wh1    = (unsigned short*) alloc((size_t)192 * 576 * 2);
  unsigned short* wl1    = (unsigned short*) alloc((size_t)192 * 576 * 2);
  unsigned short* wh2    = (unsigned short*) alloc((size_t)128 * 576 * 2);
  unsigned short* wl2    = (unsigned short*) alloc((size_t)128 * 576 * 2);
  unsigned* Apk = (unsigned*)Af;

  hipMemsetAsync(deg, 0, (size_t)NN * 4, stream);
  hipMemsetAsync(Af, 0, AELEMS * 4, stream);

  k_deg   <<<(EE + 255) / 256, 256, 0, stream>>>(src, ea, deg);
  k_fillA <<<(EE + 255) / 256, 256, 0, stream>>>(src, dst, ea, deg, Af);
  k_packA <<<(int)((AELEMS + 255) / 256), 256, 0, stream>>>(Apk, (int)AELEMS);
  k_wsplit<<<(192 * 64  + 255) / 256, 256, 0, stream>>>(w0, wh0, wl0, 192, 48,  64);
  k_wsplit<<<(192 * 576 + 255) / 256, 256, 0, stream>>>(w1, wh1, wl1, 192, 576, 576);
  k_wsplit<<<(128 * 576 + 255) / 256, 256, 0, stream>>>(w2, wh2, wl2, 128, 576, 576);
  k_embed <<<(NN * EMB_ + 255) / 256, 256, 0, stream>>>(node_ids, emb, bufA);

  constexpr int PG16  = G_ * 7;       // 448  blocks (1 n-chunk)
  constexpr int PG192 = G_ * 7 * 3;   // 1344 blocks (3 n-chunks of 64)

  // Layer 0: di=16, do=192.  Tx0=bufA, Tx1=bufB, Tx2=bufC -> bufD (packed)
  k_propm<16, 16, false><<<PG16, 256, 0, stream>>>(Apk, bufA, nullptr, bufB);
  k_propm<16, 16, true ><<<PG16, 256, 0, stream>>>(Apk, bufB, bufA, bufC);
  k_densem<16, 192, false><<<NN / 64, 256, 0, stream>>>(bufA, bufB, bufC, wh0, wl0, b0, bufD);

  // Layer 1: di=192, do=192.  Tx0=bufD -> bufC (packed)
  k_propm<192, 64, false><<<PG192, 256, 0, stream>>>(Apk, bufD, nullptr, bufA);
  k_propm<192, 64, true ><<<PG192, 256, 0, stream>>>(Apk, bufA, bufD, bufB);
  k_densem<192, 192, false><<<NN / 64, 256, 0, stream>>>(bufD, bufA, bufB, wh1, wl1, b1, bufC);

  // Layer 2: di=192, do=128.  Tx0=bufC -> bufD (fp32, feeds pool)
  k_propm<192, 64, false><<<PG192, 256, 0, stream>>>(Apk, bufC, nullptr, bufA);
  k_propm<192, 64, true ><<<PG192, 256, 0, stream>>>(Apk, bufA, bufC, bufB);
  k_densem<192, 128, true><<<NN / 64, 256, 0, stream>>>(bufC, bufA, bufB, wh2, wl2, b2, bufD);

  k_pool<<<G_, 128, 0, stream>>>((const float*)bufD, demo, feats);
  k_cls <<<G_, MODEL_, 0, stream>>>(feats, cw1, cb1, cw2, cb2, out);
}

// Round 13
// 495.863 us; speedup vs baseline: 1.9681x; 1.2987x over previous
//
#include <hip/hip_runtime.h>
#include <cstdint>

#define G_     64
#define NPG_   400
#define DEG_   40
#define NN     (G_*NPG_)        // 25600
#define EE     (G_*NPG_*DEG_)   // 1024000
#define EMB_   16
#define HID_   192
#define OC_    128
#define MODEL_ 64
#define ODIM_  2
#define DEMO_  5
#define KP_    416              // adjacency K padded to 13*32

typedef __attribute__((ext_vector_type(8))) short short8;
typedef __attribute__((ext_vector_type(4))) float f32x4;

// ---- packed split-bf16: uint = (bf16(v) << 16) | bf16(v - bf16(v)) ----
__device__ __forceinline__ float urecon(unsigned u) {
  return __uint_as_float(u & 0xFFFF0000u) + __uint_as_float(u << 16);
}
__device__ __forceinline__ unsigned upack(float v) {
  unsigned u = __float_as_uint(v);
  unsigned hb = u & 0xFFFF0000u;
  float r = v - __uint_as_float(hb);           // exact
  return hb | (__float_as_uint(r) >> 16);
}

// ---------------- degree (by src) ----------------
__global__ void k_deg(const int* __restrict__ src, const float* __restrict__ ea,
                      float* __restrict__ deg) {
  int e = blockIdx.x * 256 + threadIdx.x;
  if (e < EE) atomicAdd(&deg[src[e]], ea[e]);
}

// ---------------- dense adjacency accumulate: Af[g][dst_l][src_l] += norm ----------------
__global__ void k_fillA(const int* __restrict__ src, const int* __restrict__ dst,
                        const float* __restrict__ ea, const float* __restrict__ deg,
                        float* __restrict__ Af) {
  int e = blockIdx.x * 256 + threadIdx.x;
  if (e >= EE) return;
  int s = src[e], d = dst[e];
  float ds_ = deg[s], dd_ = deg[d];
  float a = ds_ > 0.f ? rsqrtf(ds_) : 0.f;
  float b = dd_ > 0.f ? rsqrtf(dd_) : 0.f;
  float nm = -a * ea[e] * b;
  int g = d / NPG_;                         // src same group by construction
  int dl = d - g * NPG_, sl = s - g * NPG_;
  atomicAdd(&Af[((size_t)g * NPG_ + dl) * KP_ + sl], nm);
}

// in-place pack fp32 -> split-bf16 packed uint (zeros stay zeros)
__global__ void k_packA(unsigned* __restrict__ A, int n) {
  int i = blockIdx.x * 256 + threadIdx.x;
  if (i < n) A[i] = upack(__uint_as_float(A[i]));
}

// ---------------- W pre-split: Wt_hi/lo[n][kp] ushort, transposed + zero-padded K ----------------
__global__ void k_wsplit(const float* __restrict__ W, unsigned short* __restrict__ wh,
                         unsigned short* __restrict__ wl, int don, int ktot, int kp) {
  int i = blockIdx.x * 256 + threadIdx.x;
  if (i >= don * kp) return;
  int n = i / kp, k = i - n * kp;
  float v = (k < ktot) ? W[(size_t)k * don + n] : 0.f;
  unsigned u = __float_as_uint(v);
  unsigned hb = u & 0xFFFF0000u;
  float r = v - __uint_as_float(hb);
  wh[i] = (unsigned short)(hb >> 16);
  wl[i] = (unsigned short)(__float_as_uint(r) >> 16);
}

// ---------------- embedding gather (packed output) ----------------
__global__ void k_embed(const int* __restrict__ ids, const float* __restrict__ emb,
                        unsigned* __restrict__ x) {
  int i = blockIdx.x * 256 + threadIdx.x;
  if (i >= NN * EMB_) return;
  int n = i >> 4, f = i & 15;
  x[i] = upack(emb[ids[n] * EMB_ + f]);
}

// ---------------- prop as dense MFMA GEMM: out[g] = A[g] (400x416) @ X[g] (400xDI) ----------------
// Round-13: NCH=32 for d=192 (grid 2688 = 10.5 blk/CU, LDS 13.8KB) and X-transpose
// staging via uint4 LDS writes (4 coalesced k-loads per n, one b128 write ->
// balanced 8 lanes per 4-bank group = zero extra conflicts; was 8-way scalar).
// 4 waves m-split (wave w: rows m0=w*16, NJ=NCH/16 n-frags). Split-bf16 3-term.
// XCD swizzle: group g on XCD g&7. FUSE: out = 2*(A@X) - t0.
template<int DI, int NCH, bool FUSE>
__global__ __launch_bounds__(256)
void k_propm(const unsigned* __restrict__ Ap, const unsigned* __restrict__ X,
             const unsigned* __restrict__ t0, unsigned* __restrict__ outp) {
  constexpr int KT = KP_ / 32;              // 13
  constexpr int FC = DI / NCH;              // n-chunks per group
  constexpr int NJ = NCH / 16;              // n-frags per wave
  constexpr int NU4 = (32 * NCH) / 4;       // uint4 writes for X tile
  __shared__ __align__(16) unsigned As[64][36];
  __shared__ __align__(16) unsigned Xs[NCH][36];

  const int b = blockIdx.x;
  const int xcd = b & 7;
  const int idx = b >> 3;
  const int gh = idx / (7 * FC);
  const int rem = idx % (7 * FC);
  const int rt = rem / FC, nc = rem % FC;
  const int g = (gh << 3) | xcd;
  const int rowbase = rt * 64;              // local row base (tail tile guarded)
  const int c0 = nc * NCH;
  const int nbase = g * NPG_;
  const int tid = threadIdx.x;
  const int l = tid & 63, w = tid >> 6;
  const int lm = l & 15;
  const int kq = (l >> 4) * 8;
  const int m0 = w * 16;
  const unsigned* Ag = Ap + (size_t)g * NPG_ * KP_;

  f32x4 acc[NJ];
#pragma unroll
  for (int j = 0; j < NJ; ++j) acc[j] = (f32x4)0.f;

  for (int kt = 0; kt < KT; ++kt) {
    if (kt) __syncthreads();
    const int k0 = kt * 32;
    // stage A tile 64x32 via uint4 (2 per thread); rows >=400 zeroed
#pragma unroll
    for (int it = 0; it < 2; ++it) {
      int i = tid + it * 256;
      int r = i >> 3, q = i & 7;
      int gr = rowbase + r;
      uint4 v = make_uint4(0u, 0u, 0u, 0u);
      if (gr < NPG_) v = *(const uint4*)(Ag + (size_t)gr * KP_ + k0 + q * 4);
      *(uint4*)&As[r][q * 4] = v;
    }
    // stage X chunk 32xNCH transposed -> Xs[n][kk]: per uint4, 4 coalesced
    // k-loads at one n, one b128 LDS write (balanced bank groups, no conflict)
    for (int j = tid; j < NU4; j += 256) {
      int n = j % NCH, q = j / NCH;
      int ks = k0 + q * 4;
      const unsigned* xp = X + (size_t)nbase * DI + c0 + n;
      uint4 v;
      v.x = (ks + 0 < NPG_) ? xp[(size_t)(ks + 0) * DI] : 0u;
      v.y = (ks + 1 < NPG_) ? xp[(size_t)(ks + 1) * DI] : 0u;
      v.z = (ks + 2 < NPG_) ? xp[(size_t)(ks + 2) * DI] : 0u;
      v.w = (ks + 3 < NPG_) ? xp[(size_t)(ks + 3) * DI] : 0u;
      *(uint4*)&Xs[n][q * 4] = v;
    }
    __syncthreads();

    unsigned ua[8];
    *(uint4*)&ua[0] = *(const uint4*)&As[m0 + lm][kq];
    *(uint4*)&ua[4] = *(const uint4*)&As[m0 + lm][kq + 4];
    short8 ah, al;
#pragma unroll
    for (int j2 = 0; j2 < 8; ++j2) {
      ah[j2] = (short)(ua[j2] >> 16);
      al[j2] = (short)(ua[j2] & 0xFFFFu);
    }
    short8 bh[NJ], bl[NJ];
#pragma unroll
    for (int j = 0; j < NJ; ++j) {
      unsigned ub[8];
      *(uint4*)&ub[0] = *(const uint4*)&Xs[j * 16 + lm][kq];
      *(uint4*)&ub[4] = *(const uint4*)&Xs[j * 16 + lm][kq + 4];
#pragma unroll
      for (int j2 = 0; j2 < 8; ++j2) {
        bh[j][j2] = (short)(ub[j2] >> 16);
        bl[j][j2] = (short)(ub[j2] & 0xFFFFu);
      }
    }
#pragma unroll
    for (int j = 0; j < NJ; ++j)
      acc[j] = __builtin_amdgcn_mfma_f32_16x16x32_bf16(ah, bh[j], acc[j], 0, 0, 0);
#pragma unroll
    for (int j = 0; j < NJ; ++j)
      acc[j] = __builtin_amdgcn_mfma_f32_16x16x32_bf16(ah, bl[j], acc[j], 0, 0, 0);
#pragma unroll
    for (int j = 0; j < NJ; ++j)
      acc[j] = __builtin_amdgcn_mfma_f32_16x16x32_bf16(al, bh[j], acc[j], 0, 0, 0);
  }

  const int r0 = (l >> 4) * 4;
#pragma unroll
  for (int j = 0; j < NJ; ++j) {
    int col = c0 + j * 16 + lm;
#pragma unroll
    for (int r = 0; r < 4; ++r) {
      int gr = rowbase + m0 + r0 + r;
      if (gr < NPG_) {
        size_t oi = (size_t)(nbase + gr) * DI + col;
        float v = acc[j][r];
        if constexpr (FUSE) v = 2.f * v - urecon(t0[oi]);
        outp[oi] = upack(v);
      }
    }
  }
}

// ---------------- fused dense via split-bf16 MFMA, pre-split operands (unchanged) ----------------
template<int DI, int DO, bool LAST>
__global__ __launch_bounds__(256)
void k_densem(const unsigned* __restrict__ t0, const unsigned* __restrict__ t1,
              const unsigned* __restrict__ t2,
              const unsigned short* __restrict__ wh, const unsigned short* __restrict__ wl,
              const float* __restrict__ bias, void* __restrict__ outv) {
  constexpr int KTOT = 3 * DI;
  constexpr int KT = (KTOT + 31) / 32;
  constexpr int KP = KT * 32;
  constexpr int NT = DO / 16;
  constexpr int XS = 36;
  constexpr int WS = 40;
  __shared__ __align__(16) unsigned Xu[64][XS];
  __shared__ __align__(16) unsigned short Whs[DO][WS];
  __shared__ __align__(16) unsigned short Wls[DO][WS];

  const int tid = threadIdx.x;
  const int rowbase = blockIdx.x * 64;
  const int l = tid & 63, w = tid >> 6;
  const int lm = l & 15;
  const int kb = (l >> 4) * 8;

  f32x4 acc[NT];
#pragma unroll
  for (int j = 0; j < NT; ++j) acc[j] = (f32x4)0.f;

  for (int kt = 0; kt < KT; ++kt) {
    if (kt) __syncthreads();
    const int k0 = kt * 32;
    if constexpr (DI % 32 == 0) {
      const int bb = k0 / DI, d0 = k0 - bb * DI;
      const unsigned* tb = bb == 0 ? t0 : (bb == 1 ? t1 : t2);
#pragma unroll
      for (int it = 0; it < 2; ++it) {
        int i = tid + it * 256;
        int r = i >> 3, q = i & 7;
        ((uint4*)&Xu[r][0])[q] = ((const uint4*)(tb + (size_t)(rowbase + r) * DI + d0))[q];
      }
    } else {
      for (int i = tid; i < 64 * 32; i += 256) {
        int r = i >> 5, kk = i & 31, kg = k0 + kk;
        unsigned u = 0;
        if (kg < KTOT) {
          int bb = kg / DI, d = kg - bb * DI;
          const unsigned* tb = bb == 0 ? t0 : (bb == 1 ? t1 : t2);
          u = tb[(size_t)(rowbase + r) * DI + d];
        }
        Xu[r][kk] = u;
      }
    }
    for (int i = tid; i < DO * 4; i += 256) {
      int n = i >> 2, q = i & 3;
      ((uint4*)&Whs[n][0])[q] = ((const uint4*)(wh + (size_t)n * KP + k0))[q];
    }
    for (int i = tid; i < DO * 4; i += 256) {
      int n = i >> 2, q = i & 3;
      ((uint4*)&Wls[n][0])[q] = ((const uint4*)(wl + (size_t)n * KP + k0))[q];
    }
    __syncthreads();

    unsigned ua[8];
    *(uint4*)&ua[0] = *(const uint4*)&Xu[w * 16 + lm][kb];
    *(uint4*)&ua[4] = *(const uint4*)&Xu[w * 16 + lm][kb + 4];
    short8 ah, al;
#pragma unroll
    for (int j2 = 0; j2 < 8; ++j2) {
      ah[j2] = (short)(ua[j2] >> 16);
      al[j2] = (short)(ua[j2] & 0xFFFFu);
    }
#pragma unroll
    for (int j = 0; j < NT; ++j) {
      int n = j * 16 + lm;
      short8 bh = *(const short8*)&Whs[n][kb];
      short8 bl = *(const short8*)&Wls[n][kb];
      acc[j] = __builtin_amdgcn_mfma_f32_16x16x32_bf16(ah, bh, acc[j], 0, 0, 0);
      acc[j] = __builtin_amdgcn_mfma_f32_16x16x32_bf16(ah, bl, acc[j], 0, 0, 0);
      acc[j] = __builtin_amdgcn_mfma_f32_16x16x32_bf16(al, bh, acc[j], 0, 0, 0);
    }
  }

  const int r0 = (l >> 4) * 4;
#pragma unroll
  for (int j = 0; j < NT; ++j) {
    int col = j * 16 + lm;
    float bv = bias[col];
#pragma unroll
    for (int r = 0; r < 4; ++r) {
      int row = rowbase + w * 16 + r0 + r;
      float val = acc[j][r] + bv;
      if (LAST) ((float*)outv)[(size_t)row * DO + col] = val;
      else      ((unsigned*)outv)[(size_t)row * DO + col] = upack(val);
    }
  }
}

// ---------------- mean pool per graph + concat demographics ----------------
__global__ void k_pool(const float* __restrict__ x, const float* __restrict__ demo,
                       float* __restrict__ feats) {
  int g = blockIdx.x, j = threadIdx.x;  // 128 threads
  const float* p = x + (size_t)g * NPG_ * OC_;
  float s = 0.f;
  for (int n = 0; n < NPG_; ++n) s += p[n * OC_ + j];
  feats[g * (OC_ + DEMO_) + j] = s * (1.f / NPG_);
  if (j < DEMO_) feats[g * (OC_ + DEMO_) + OC_ + j] = demo[g * DEMO_ + j];
}

// ---------------- classifier MLP ----------------
__global__ void k_cls(const float* __restrict__ feats,
                      const float* __restrict__ w1, const float* __restrict__ b1,
                      const float* __restrict__ w2, const float* __restrict__ b2,
                      float* __restrict__ out) {
  int g = blockIdx.x, j = threadIdx.x;  // 64 threads
  __shared__ float h[MODEL_];
  const float* f = feats + g * (OC_ + DEMO_);
  float a = b1[j];
  for (int i = 0; i < OC_ + DEMO_; ++i) a += f[i] * w1[i * MODEL_ + j];
  h[j] = fmaxf(a, 0.f);
  __syncthreads();
  if (j < ODIM_) {
    float o = b2[j];
    for (int i = 0; i < MODEL_; ++i) o += h[i] * w2[i * ODIM_ + j];
    out[g * ODIM_ + j] = o;
  }
}

extern "C" void kernel_launch(void* const* d_in, const int* in_sizes, int n_in,
                              void* d_out, int out_size, void* d_ws, size_t ws_size,
                              hipStream_t stream) {
  const int*   node_ids = (const int*)d_in[0];
  const int*   ei   = (const int*)d_in[1];
  const int*   src  = ei;
  const int*   dst  = ei + EE;
  const float* ea   = (const float*)d_in[3];
  const float* demo = (const float*)d_in[4];
  const float* emb  = (const float*)d_in[5];
  const float* w0   = (const float*)d_in[6];
  const float* b0   = (const float*)d_in[7];
  const float* w1   = (const float*)d_in[8];
  const float* b1   = (const float*)d_in[9];
  const float* w2   = (const float*)d_in[10];
  const float* b2   = (const float*)d_in[11];
  const float* cw1  = (const float*)d_in[12];
  const float* cb1  = (const float*)d_in[13];
  const float* cw2  = (const float*)d_in[14];
  const float* cb2  = (const float*)d_in[15];
  float* out = (float*)d_out;

  char* wp = (char*)d_ws;
  auto alloc = [&](size_t bytes) {
    char* p = wp;
    wp += (bytes + 255) & ~(size_t)255;
    return (void*)p;
  };
  constexpr size_t AELEMS = (size_t)G_ * NPG_ * KP_;   // 10,649,600
  float*          deg    = (float*)          alloc((size_t)NN * 4);
  float*          Af     = (float*)          alloc(AELEMS * 4 + 256); // +tail pad
  unsigned*       bufA   = (unsigned*)       alloc((size_t)NN * HID_ * 4);
  unsigned*       bufB   = (unsigned*)       alloc((size_t)NN * HID_ * 4);
  unsigned*       bufC   = (unsigned*)       alloc((size_t)NN * HID_ * 4);
  unsigned*       bufD   = (unsigned*)       alloc((size_t)NN * HID_ * 4);
  float*          feats  = (float*)          alloc((size_t)G_ * (OC_ + DEMO_) * 4);
  unsigned short* wh0    = (unsigned short*) alloc((size_t)192 * 64 * 2);
  unsigned short* wl0    = (unsigned short*) alloc((size_t)192 * 64 * 2);
  unsigned short* wh1    = (unsigned short*) alloc((size_t)192 * 576 * 2);
  unsigned short* wl1    = (unsigned short*) alloc((size_t)192 * 576 * 2);
  unsigned short* wh2    = (unsigned short*) alloc((size_t)128 * 576 * 2);
  unsigned short* wl2    = (unsigned short*) alloc((size_t)128 * 576 * 2);
  unsigned* Apk = (unsigned*)Af;

  hipMemsetAsync(deg, 0, (size_t)NN * 4, stream);
  hipMemsetAsync(Af, 0, AELEMS * 4, stream);

  k_deg   <<<(EE + 255) / 256, 256, 0, stream>>>(src, ea, deg);
  k_fillA <<<(EE + 255) / 256, 256, 0, stream>>>(src, dst, ea, deg, Af);
  k_packA <<<(int)((AELEMS + 255) / 256), 256, 0, stream>>>(Apk, (int)AELEMS);
  k_wsplit<<<(192 * 64  + 255) / 256, 256, 0, stream>>>(w0, wh0, wl0, 192, 48,  64);
  k_wsplit<<<(192 * 576 + 255) / 256, 256, 0, stream>>>(w1, wh1, wl1, 192, 576, 576);
  k_wsplit<<<(128 * 576 + 255) / 256, 256, 0, stream>>>(w2, wh2, wl2, 128, 576, 576);
  k_embed <<<(NN * EMB_ + 255) / 256, 256, 0, stream>>>(node_ids, emb, bufA);

  constexpr int PG16  = G_ * 7;       // 448  blocks (NCH=16, 1 n-chunk)
  constexpr int PG192 = G_ * 7 * 6;   // 2688 blocks (6 n-chunks of 32)

  // Layer 0: di=16, do=192.  Tx0=bufA, Tx1=bufB, Tx2=bufC -> bufD (packed)
  k_propm<16, 16, false><<<PG16, 256, 0, stream>>>(Apk, bufA, nullptr, bufB);
  k_propm<16, 16, true ><<<PG16, 256, 0, stream>>>(Apk, bufB, bufA, bufC);
  k_densem<16, 192, false><<<NN / 64, 256, 0, stream>>>(bufA, bufB, bufC, wh0, wl0, b0, bufD);

  // Layer 1: di=192, do=192.  Tx0=bufD -> bufC (packed)
  k_propm<192, 32, false><<<PG192, 256, 0, stream>>>(Apk, bufD, nullptr, bufA);
  k_propm<192, 32, true ><<<PG192, 256, 0, stream>>>(Apk, bufA, bufD, bufB);
  k_densem<192, 192, false><<<NN / 64, 256, 0, stream>>>(bufD, bufA, bufB, wh1, wl1, b1, bufC);

  // Layer 2: di=192, do=128.  Tx0=bufC -> bufD (fp32, feeds pool)
  k_propm<192, 32, false><<<PG192, 256, 0, stream>>>(Apk, bufC, nullptr, bufA);
  k_propm<192, 32, true ><<<PG192, 256, 0, stream>>>(Apk, bufA, bufC, bufB);
  k_densem<192, 128, true><<<NN / 64, 256, 0, stream>>>(bufC, bufA, bufB, wh2, wl2, b2, bufD);

  k_pool<<<G_, 128, 0, stream>>>((const float*)bufD, demo, feats);
  k_cls <<<G_, MODEL_, 0, stream>>>(feats, cw1, cb1, cw2, cb2, out);
}